// Round 1
// baseline (159.616 us; speedup 1.0000x reference)
//
#include <hip/hip_runtime.h>

#define TG_D      4096
#define TG_BLOCK  256
#define TG_EPT    16            // elements per thread
#define TG_CHUNKS (TG_D / 4)    // 1024 float4/uint4 chunks per row

// XOR swizzle on 16B-chunk index: makes BOTH the strided (lane-consecutive)
// pattern and the contiguous-per-thread (64B lane stride) pattern hit the
// optimal 8-phase minimum for wave64 ds_*_b128 (32 banks x 4B).
__device__ __forceinline__ int tg_swz(int c) { return c ^ ((c >> 3) & 7); }

// Order-preserving monotone key for fp32 (ascending float -> ascending uint).
__device__ __forceinline__ unsigned int tg_key(float f) {
  unsigned int b = __float_as_uint(f);
  return (b & 0x80000000u) ? ~b : (b | 0x80000000u);
}
__device__ __forceinline__ unsigned int tg_dec_bits(unsigned int kk) {
  return (kk & 0x80000000u) ? (kk & 0x7FFFFFFFu) : ~kk;
}

// Bit-exact replication attempt of jax.nn.gelu(approximate=False) on XLA CPU:
//   g = x * (erf(x / float32(sqrt(2))) + 1) / 2
// erf f32 lowered as XLA's EmitErfF32 == Eigen generic_fast_erf_float:
//   clamp(x,-4,4); rational x*P(x^2)/Q(x^2), Horner with fused FMA, IEEE div.
__device__ __forceinline__ float tg_gelu(float x) {
#pragma clang fp contract(off)
  float d  = x / 0x1.6a09e6p+0f;            // IEEE divide by float32(sqrt(2))
  float xc = fmaxf(fminf(d, 4.0f), -4.0f);
  float x2 = xc * xc;
  float p = -2.72614225801306e-10f;
  p = __builtin_fmaf(p, x2,  2.77068142495902e-08f);
  p = __builtin_fmaf(p, x2, -2.10102402082508e-06f);
  p = __builtin_fmaf(p, x2, -5.69250639462346e-05f);
  p = __builtin_fmaf(p, x2, -7.34990630326855e-04f);
  p = __builtin_fmaf(p, x2, -2.95459980854025e-03f);
  p = __builtin_fmaf(p, x2, -1.60960333262415e-02f);
  float q = -1.45660718464996e-05f;
  q = __builtin_fmaf(q, x2, -2.13374055278905e-04f);
  q = __builtin_fmaf(q, x2, -1.68282697438203e-03f);
  q = __builtin_fmaf(q, x2, -7.37332916720468e-03f);
  q = __builtin_fmaf(q, x2, -1.42647390514189e-02f);
  float num = xc * p;
  float e   = num / q;                      // IEEE divide
  float s   = e + 1.0f;
  float m   = x * s;
  return m * 0.5f;                          // exact halving == /2
}

__global__ __launch_bounds__(TG_BLOCK) void topk_gelu_kernel(
    const float* __restrict__ x, const int* __restrict__ kptr,
    float* __restrict__ out) {
  __shared__ uint4 buf[TG_CHUNKS];          // 16 KiB: keys, later output bits
  __shared__ unsigned int hist[256];
  __shared__ unsigned int sfx[256];
  __shared__ unsigned int waveTot[4];
  __shared__ unsigned int shSelB, shSelGT;

  const int tid  = threadIdx.x;
  const int lane = tid & 63;
  const int wv   = tid >> 6;
  const int row  = blockIdx.x;
  const unsigned int k = (unsigned int)(*kptr);

  const float* xr  = x   + (size_t)row * TG_D;
  float*       outr = out + (size_t)row * TG_D;

  // ---- stage 1: coalesced load, gelu, key-encode, swizzled LDS store ----
#pragma unroll
  for (int c = 0; c < 4; ++c) {
    int chunk = tid + c * TG_BLOCK;
    float4 v = reinterpret_cast<const float4*>(xr)[chunk];
    uint4 kk;
    kk.x = tg_key(tg_gelu(v.x));
    kk.y = tg_key(tg_gelu(v.y));
    kk.z = tg_key(tg_gelu(v.z));
    kk.w = tg_key(tg_gelu(v.w));
    buf[tg_swz(chunk)] = kk;
  }
  __syncthreads();

  // ---- stage 2: each thread pulls its contiguous 16 keys into VGPRs ----
  unsigned int key[TG_EPT];
#pragma unroll
  for (int j = 0; j < 4; ++j) {
    uint4 kk = buf[tg_swz(tid * 4 + j)];
    key[4 * j + 0] = kk.x;
    key[4 * j + 1] = kk.y;
    key[4 * j + 2] = kk.z;
    key[4 * j + 3] = kk.w;
  }

  // ---- radix select: find key of k-th largest (T) and kRem equals to keep ----
  unsigned int prefix = 0;
  unsigned int kRem   = k;
#pragma unroll
  for (int p = 0; p < 4; ++p) {
    const int shift = 24 - 8 * p;
    hist[tid] = 0;
    __syncthreads();
    const unsigned int pmask = (p == 0) ? 0u : (0xFFFFFFFFu << (shift + 8));
#pragma unroll
    for (int j = 0; j < TG_EPT; ++j) {
      if ((key[j] & pmask) == prefix)
        atomicAdd(&hist[(key[j] >> shift) & 0xFF], 1u);
    }
    __syncthreads();
    // suffix scan over 256 bins: sfx[b] = # candidates with byte >= b
    unsigned int v = hist[tid];
#pragma unroll
    for (int dlt = 1; dlt < 64; dlt <<= 1) {
      unsigned int o = __shfl_down(v, dlt, 64);
      v += (lane + dlt < 64) ? o : 0u;
    }
    if (lane == 0) waveTot[wv] = v;
    __syncthreads();
    unsigned int hi = 0;
#pragma unroll
    for (int w2 = 0; w2 < 4; ++w2)
      if (w2 > wv) hi += waveTot[w2];
    unsigned int sGE = v + hi;
    sfx[tid] = sGE;
    __syncthreads();
    unsigned int sGT = (tid == 255) ? 0u : sfx[tid + 1];
    if (sGE >= kRem && sGT < kRem) { shSelB = (unsigned int)tid; shSelGT = sGT; }
    __syncthreads();
    prefix |= (shSelB << shift);
    kRem   -= shSelGT;
  }
  const unsigned int T = prefix;

  // ---- tie-break by ascending index among key == T ----
  unsigned int cnt = 0;
#pragma unroll
  for (int j = 0; j < TG_EPT; ++j) cnt += (key[j] == T) ? 1u : 0u;
  unsigned int pv = cnt;
#pragma unroll
  for (int dlt = 1; dlt < 64; dlt <<= 1) {
    unsigned int o = __shfl_up(pv, dlt, 64);
    pv += (lane >= dlt) ? o : 0u;
  }
  if (lane == 63) waveTot[wv] = pv;     // wave total (safe: barriers since last read)
  __syncthreads();
  unsigned int base = 0;
#pragma unroll
  for (int w2 = 0; w2 < 4; ++w2)
    if (w2 < wv) base += waveTot[w2];
  unsigned int off = base + pv - cnt;   // exclusive prefix, global index order

  // ---- write selected values (decoded) / zeros into LDS ----
#pragma unroll
  for (int j = 0; j < 4; ++j) {
    unsigned int r[4];
#pragma unroll
    for (int t2 = 0; t2 < 4; ++t2) {
      unsigned int kj = key[4 * j + t2];
      bool keep;
      if (kj > T)       keep = true;
      else if (kj == T) { keep = (off < kRem); ++off; }
      else              keep = false;
      r[t2] = keep ? tg_dec_bits(kj) : 0u;
    }
    uint4 o4; o4.x = r[0]; o4.y = r[1]; o4.z = r[2]; o4.w = r[3];
    buf[tg_swz(tid * 4 + j)] = o4;
  }
  __syncthreads();

  // ---- coalesced store ----
#pragma unroll
  for (int c = 0; c < 4; ++c) {
    int chunk = tid + c * TG_BLOCK;
    uint4 o4 = buf[tg_swz(chunk)];
    float4 f4;
    f4.x = __uint_as_float(o4.x);
    f4.y = __uint_as_float(o4.y);
    f4.z = __uint_as_float(o4.z);
    f4.w = __uint_as_float(o4.w);
    reinterpret_cast<float4*>(outr)[chunk] = f4;
  }
}

extern "C" void kernel_launch(void* const* d_in, const int* in_sizes, int n_in,
                              void* d_out, int out_size, void* d_ws, size_t ws_size,
                              hipStream_t stream) {
  const float* x = (const float*)d_in[0];
  const int* kp  = (const int*)d_in[1];
  float* out     = (float*)d_out;
  int rows = in_sizes[0] / TG_D;   // 16384 for (4,4096,4096)
  topk_gelu_kernel<<<rows, TG_BLOCK, 0, stream>>>(x, kp, out);
}

// Round 2
// 151.444 us; speedup vs baseline: 1.0540x; 1.0540x over previous
//
#include <hip/hip_runtime.h>

#define TG_D    4096
#define TG_BLK  256
#define TG_CAP  1024
#define TG_T0   0.90f

__device__ __forceinline__ unsigned tg_key(float f) {
  unsigned b = __float_as_uint(f);
  return (b & 0x80000000u) ? ~b : (b | 0x80000000u);
}
__device__ __forceinline__ unsigned tg_dec(unsigned k) {
  return (k & 0x80000000u) ? (k & 0x7FFFFFFFu) : ~k;
}

// Bit-exact replication of jax.nn.gelu(approximate=False) on XLA CPU
// (verified round 1: absmax == bf16 storage ulp). Do not touch.
__device__ __forceinline__ float tg_gelu(float x) {
#pragma clang fp contract(off)
  float d  = x / 0x1.6a09e6p+0f;            // IEEE divide by float32(sqrt(2))
  float xc = fmaxf(fminf(d, 4.0f), -4.0f);
  float x2 = xc * xc;
  float p = -2.72614225801306e-10f;
  p = __builtin_fmaf(p, x2,  2.77068142495902e-08f);
  p = __builtin_fmaf(p, x2, -2.10102402082508e-06f);
  p = __builtin_fmaf(p, x2, -5.69250639462346e-05f);
  p = __builtin_fmaf(p, x2, -7.34990630326855e-04f);
  p = __builtin_fmaf(p, x2, -2.95459980854025e-03f);
  p = __builtin_fmaf(p, x2, -1.60960333262415e-02f);
  float q = -1.45660718464996e-05f;
  q = __builtin_fmaf(q, x2, -2.13374055278905e-04f);
  q = __builtin_fmaf(q, x2, -1.68282697438203e-03f);
  q = __builtin_fmaf(q, x2, -7.37332916720468e-03f);
  q = __builtin_fmaf(q, x2, -1.42647390514189e-02f);
  float num = xc * p;
  float e   = num / q;                      // IEEE divide
  float s   = e + 1.0f;
  float m   = x * s;
  return m * 0.5f;
}

// Suffix-scan 4-way-split 256-bin histogram, pick bin where suffix count
// crosses kRem. sel[0]=byte, sel[1]=count strictly-greater, sel[2]=count equal.
__device__ __forceinline__ void tg_pick_byte(unsigned (*h)[256], unsigned* sfx,
                                             unsigned* wtot, unsigned* sel,
                                             unsigned kRem, int tid, int lane, int wv) {
  __syncthreads();                               // histogram atomics done
  unsigned v = h[0][tid] + h[1][tid] + h[2][tid] + h[3][tid];
#pragma unroll
  for (int d = 1; d < 64; d <<= 1) {
    unsigned o = __shfl_down(v, d, 64);
    v += (lane + d < 64) ? o : 0u;
  }
  if (lane == 0) wtot[wv] = v;
  __syncthreads();
  unsigned hi = 0;
#pragma unroll
  for (int w = 0; w < 4; ++w)
    if (w > wv) hi += wtot[w];
  unsigned sGE = v + hi;                         // # keys with bin >= tid
  sfx[tid] = sGE;
  __syncthreads();
  unsigned sGT = (tid == 255) ? 0u : sfx[tid + 1];
  if (sGE >= kRem && sGT < kRem) { sel[0] = (unsigned)tid; sel[1] = sGT; sel[2] = sGE - sGT; }
  __syncthreads();
}

__global__ __launch_bounds__(TG_BLK) void topk_gelu_kernel(
    const float* __restrict__ x, const int* __restrict__ kptr,
    float* __restrict__ out) {
  __shared__ float          cx[TG_CAP];          // candidate x
  __shared__ unsigned       ckey[TG_CAP];        // candidate gelu key
  __shared__ unsigned short cidx[TG_CAP];        // candidate row-slot (0..4095)
  __shared__ unsigned       hist[4][256];        // per-wave split histograms
  __shared__ unsigned       sfx[256];
  __shared__ unsigned       wtot[4];
  __shared__ unsigned       wbase[4];
  __shared__ unsigned       sel[3];
  __shared__ unsigned       nCand;
  __shared__ unsigned       tieMask[128];        // 4096-bit tie bitmap

  const int tid = threadIdx.x, lane = tid & 63, wv = tid >> 6;
  const unsigned k = (unsigned)(*kptr);
  const float* xr  = x   + (size_t)blockIdx.x * TG_D;
  float*       outr = out + (size_t)blockIdx.x * TG_D;

  if (tid == 0) nCand = 0;

  // ---- coalesced load; elements stay in VGPRs (strided ownership) ----
  float xv[16];
#pragma unroll
  for (int c = 0; c < 4; ++c) {
    float4 v = reinterpret_cast<const float4*>(xr)[tid + c * TG_BLK];
    xv[4*c+0] = v.x; xv[4*c+1] = v.y; xv[4*c+2] = v.z; xv[4*c+3] = v.w;
  }
  __syncthreads();                               // nCand init visible

  // ---- compact candidates (x >= T0) into LDS via wave ballot scan ----
  unsigned candMask = 0;
  unsigned short pos[16];
  unsigned wcnt = 0;
  const unsigned long long below = (1ull << lane) - 1ull;
#pragma unroll
  for (int e = 0; e < 16; ++e) {
    bool c = (xv[e] >= TG_T0);
    unsigned long long mb = __ballot(c);
    if (c) { candMask |= (1u << e); pos[e] = (unsigned short)(wcnt + (unsigned)__popcll(mb & below)); }
    wcnt += (unsigned)__popcll(mb);
  }
  if (lane == 0) wbase[wv] = atomicAdd(&nCand, wcnt);
  __syncthreads();
  const unsigned base = wbase[wv];
#pragma unroll
  for (int e = 0; e < 16; ++e) {
    if (candMask & (1u << e)) {
      unsigned p = base + pos[e];
      if (p < TG_CAP) {
        cx[p]   = xv[e];
        cidx[p] = (unsigned short)((tid + (e >> 2) * TG_BLK) * 4 + (e & 3));
      }
      pos[e] = (unsigned short)p;
    }
  }
  __syncthreads();
  const unsigned n0 = nCand;

  bool slow = !(n0 >= k + 64u && n0 <= (unsigned)TG_CAP);
  unsigned Tg = 0, kRemF = 0, cntEq = 0;
  unsigned gk[16];                               // slow-path keys

  if (!slow) {
    // ---- dense gelu on compacted candidates only (~18% of elements) ----
    for (unsigned i = tid; i < n0; i += TG_BLK) ckey[i] = tg_key(tg_gelu(cx[i]));
    // ---- 4-pass radix select rank k over candidate gelu keys ----
    unsigned prefix = 0, kRem = k;
#pragma unroll
    for (int p = 0; p < 4; ++p) {
      const int shift = 24 - 8 * p;
      hist[0][tid] = 0; hist[1][tid] = 0; hist[2][tid] = 0; hist[3][tid] = 0;
      __syncthreads();
      const unsigned pmask = p ? (0xFFFFFFFFu << (shift + 8)) : 0u;
      for (unsigned i = tid; i < n0; i += TG_BLK) {
        unsigned kk = ckey[i];
        if ((kk & pmask) == prefix) atomicAdd(&hist[wv][(kk >> shift) & 255], 1u);
      }
      tg_pick_byte(hist, sfx, wtot, sel, kRem, tid, lane, wv);
      prefix |= sel[0] << shift;
      kRem   -= sel[1];
    }
    Tg = prefix; kRemF = kRem; cntEq = sel[2];
    // band-safety guard: threshold must sit safely above gelu(T0)
    float fTg = __uint_as_float(tg_dec(Tg));
    float gT0 = tg_gelu(TG_T0);
    if (!(fTg > gT0 + 1e-6f)) slow = true;
  }

  if (slow) {
    // ---- general path: gelu + radix over all 4096 elements (rare) ----
#pragma unroll
    for (int e = 0; e < 16; ++e) gk[e] = tg_key(tg_gelu(xv[e]));
    unsigned prefix = 0, kRem = k;
#pragma unroll
    for (int p = 0; p < 4; ++p) {
      const int shift = 24 - 8 * p;
      __syncthreads();
      hist[0][tid] = 0; hist[1][tid] = 0; hist[2][tid] = 0; hist[3][tid] = 0;
      __syncthreads();
      const unsigned pmask = p ? (0xFFFFFFFFu << (shift + 8)) : 0u;
#pragma unroll
      for (int e = 0; e < 16; ++e)
        if ((gk[e] & pmask) == prefix) atomicAdd(&hist[wv][(gk[e] >> shift) & 255], 1u);
      tg_pick_byte(hist, sfx, wtot, sel, kRem, tid, lane, wv);
      prefix |= sel[0] << shift;
      kRem   -= sel[1];
    }
    Tg = prefix; kRemF = kRem; cntEq = sel[2];
  }

  // ---- tie handling: only when #equal != #to-keep (almost never) ----
  const bool needTie = (cntEq != kRemF);
  if (needTie) {
    if (tid < 128) tieMask[tid] = 0;
    __syncthreads();
    if (slow) {
#pragma unroll
      for (int e = 0; e < 16; ++e)
        if (gk[e] == Tg) {
          unsigned s = (tid + (e >> 2) * TG_BLK) * 4 + (e & 3);
          atomicOr(&tieMask[s >> 5], 1u << (s & 31));
        }
    } else {
      for (unsigned i = tid; i < n0; i += TG_BLK)
        if (ckey[i] == Tg) {
          unsigned s = cidx[i];
          atomicOr(&tieMask[s >> 5], 1u << (s & 31));
        }
    }
    __syncthreads();
  }

  // ---- per-element verdict + coalesced float4 store ----
#pragma unroll
  for (int c = 0; c < 4; ++c) {
    float r[4];
#pragma unroll
    for (int j = 0; j < 4; ++j) {
      const int e = 4 * c + j;
      float ov = 0.0f;
      unsigned kk = 0;
      bool have;
      if (slow) { kk = gk[e]; have = true; }
      else      { have = (candMask >> e) & 1u; if (have) kk = ckey[pos[e]]; }
      if (have) {
        bool keep = (kk > Tg);
        if (!keep && kk == Tg) {
          if (!needTie) keep = true;
          else {
            unsigned s = (unsigned)((tid + c * TG_BLK) * 4 + j);
            unsigned rank = __popc(tieMask[s >> 5] & ((1u << (s & 31)) - 1u));
            for (unsigned w = 0; w < (s >> 5); ++w) rank += __popc(tieMask[w]);
            keep = rank < kRemF;
          }
        }
        if (keep) ov = __uint_as_float(tg_dec(kk));
      }
      r[j] = ov;
    }
    float4 o4; o4.x = r[0]; o4.y = r[1]; o4.z = r[2]; o4.w = r[3];
    reinterpret_cast<float4*>(outr)[tid + c * TG_BLK] = o4;
  }
}

extern "C" void kernel_launch(void* const* d_in, const int* in_sizes, int n_in,
                              void* d_out, int out_size, void* d_ws, size_t ws_size,
                              hipStream_t stream) {
  const float* x = (const float*)d_in[0];
  const int* kp  = (const int*)d_in[1];
  float* out     = (float*)d_out;
  int rows = in_sizes[0] / TG_D;
  topk_gelu_kernel<<<rows, TG_BLK, 0, stream>>>(x, kp, out);
}

// Round 3
// 127.182 us; speedup vs baseline: 1.2550x; 1.1908x over previous
//
#include <hip/hip_runtime.h>

#define TG_D    4096
#define TG_BLK  256
#define TG_CAP  1024
#define TG_T0   0.90f
#define TG_GT0  0.735f   // conservative upper bound on gelu(TG_T0)=0.73426

__device__ __forceinline__ unsigned tg_key(float f) {
  unsigned b = __float_as_uint(f);
  return (b & 0x80000000u) ? ~b : (b | 0x80000000u);
}
__device__ __forceinline__ unsigned tg_dec(unsigned k) {
  return (k & 0x80000000u) ? (k & 0x7FFFFFFFu) : ~k;
}

// Bit-exact replication of jax.nn.gelu(approximate=False) on XLA CPU
// (verified r1/r2: absmax == bf16 storage ulp). Do not touch.
__device__ __forceinline__ float tg_gelu(float x) {
#pragma clang fp contract(off)
  float d  = x / 0x1.6a09e6p+0f;            // IEEE divide by float32(sqrt(2))
  float xc = fmaxf(fminf(d, 4.0f), -4.0f);
  float x2 = xc * xc;
  float p = -2.72614225801306e-10f;
  p = __builtin_fmaf(p, x2,  2.77068142495902e-08f);
  p = __builtin_fmaf(p, x2, -2.10102402082508e-06f);
  p = __builtin_fmaf(p, x2, -5.69250639462346e-05f);
  p = __builtin_fmaf(p, x2, -7.34990630326855e-04f);
  p = __builtin_fmaf(p, x2, -2.95459980854025e-03f);
  p = __builtin_fmaf(p, x2, -1.60960333262415e-02f);
  float q = -1.45660718464996e-05f;
  q = __builtin_fmaf(q, x2, -2.13374055278905e-04f);
  q = __builtin_fmaf(q, x2, -1.68282697438203e-03f);
  q = __builtin_fmaf(q, x2, -7.37332916720468e-03f);
  q = __builtin_fmaf(q, x2, -1.42647390514189e-02f);
  float num = xc * p;
  float e   = num / q;                      // IEEE divide
  float s   = e + 1.0f;
  float m   = x * s;
  return m * 0.5f;
}

// Pick the histogram bin where the suffix count crosses kRem.
// sel[0]=byte, sel[1]=count strictly greater, sel[2]=count equal (bin count).
// 3 barriers total (incl. the post-atomics one).
__device__ __forceinline__ void tg_pick_byte(unsigned (*h)[256], unsigned* wtot,
                                             unsigned* sel, unsigned kRem,
                                             int tid, int lane, int wv) {
  __syncthreads();                               // histogram atomics done
  unsigned cb = h[0][tid] + h[1][tid] + h[2][tid] + h[3][tid];
  unsigned v = cb;
#pragma unroll
  for (int d = 1; d < 64; d <<= 1) {
    unsigned o = __shfl_down(v, d, 64);
    v += (lane + d < 64) ? o : 0u;
  }
  if (lane == 0) wtot[wv] = v;
  __syncthreads();
  unsigned hi = 0;
#pragma unroll
  for (int w = 0; w < 4; ++w)
    if (w > wv) hi += wtot[w];
  unsigned sGE = v + hi;                         // # keys with bin >= tid
  unsigned sGT = sGE - cb;                       // # keys with bin >  tid
  if (sGE >= kRem && sGT < kRem) { sel[0] = (unsigned)tid; sel[1] = sGT; sel[2] = cb; }
  __syncthreads();
}

__global__ __launch_bounds__(TG_BLK) void topk_gelu_kernel(
    const float* __restrict__ x, const int* __restrict__ kptr,
    float* __restrict__ out) {
  __shared__ float    cx[TG_CAP];                // candidate x (thread-major order)
  __shared__ unsigned ckey[TG_CAP];              // candidate gelu keys
  __shared__ unsigned hist[4][256];              // per-wave split histograms
  __shared__ unsigned wtot[4];
  __shared__ unsigned sel[3];
  __shared__ unsigned tieMask[128];              // 4096-bit tie bitmap

  const int tid = threadIdx.x, lane = tid & 63, wv = tid >> 6;
  const unsigned k = (unsigned)(*kptr);
  const float* xr   = x   + (size_t)blockIdx.x * TG_D;
  float*       outr = out + (size_t)blockIdx.x * TG_D;

  // ---- coalesced load; elements stay in VGPRs (strided ownership) ----
  float xv[16];
#pragma unroll
  for (int c = 0; c < 4; ++c) {
    float4 v = reinterpret_cast<const float4*>(xr)[tid + c * TG_BLK];
    xv[4*c+0] = v.x; xv[4*c+1] = v.y; xv[4*c+2] = v.z; xv[4*c+3] = v.w;
  }

  // ---- candidate mask + single block scan (thread-major compaction) ----
  unsigned candMask = 0;
#pragma unroll
  for (int e = 0; e < 16; ++e)
    if (xv[e] >= TG_T0) candMask |= (1u << e);
  const unsigned cnt = (unsigned)__popc(candMask);
  unsigned inc = cnt;
#pragma unroll
  for (int d = 1; d < 64; d <<= 1) {
    unsigned o = __shfl_up(inc, d, 64);
    if (lane >= d) inc += o;
  }
  if (lane == 63) wtot[wv] = inc;
  __syncthreads();
  unsigned base = inc - cnt;
#pragma unroll
  for (int w = 0; w < 4; ++w)
    if (w < wv) base += wtot[w];
  const unsigned n0 = wtot[0] + wtot[1] + wtot[2] + wtot[3];

  // each thread writes its candidates to its own contiguous LDS range
  if (n0 <= (unsigned)TG_CAP) {
    unsigned p = base;
#pragma unroll
    for (int e = 0; e < 16; ++e)
      if (candMask & (1u << e)) cx[p++] = xv[e];
  }
  __syncthreads();

  bool slow = !(n0 >= k + 64u && n0 <= (unsigned)TG_CAP);
  unsigned Tg = 0, kRemF = 0, cntEq = 0;
  unsigned gk[16];                               // slow-path keys

  if (!slow) {
    // ---- dense gelu on compacted candidates only (~18% of elements) ----
    for (unsigned i = tid; i < n0; i += TG_BLK) ckey[i] = tg_key(tg_gelu(cx[i]));
    // ---- 4-pass radix select rank k over candidate gelu keys ----
    unsigned prefix = 0, kRem = k;
#pragma unroll
    for (int p = 0; p < 4; ++p) {
      const int shift = 24 - 8 * p;
      hist[0][tid] = 0; hist[1][tid] = 0; hist[2][tid] = 0; hist[3][tid] = 0;
      __syncthreads();
      const unsigned pmask = p ? (0xFFFFFFFFu << (shift + 8)) : 0u;
      for (unsigned i = tid; i < n0; i += TG_BLK) {
        unsigned kk = ckey[i];
        if ((kk & pmask) == prefix) atomicAdd(&hist[wv][(kk >> shift) & 255], 1u);
      }
      tg_pick_byte(hist, wtot, sel, kRem, tid, lane, wv);
      prefix |= sel[0] << shift;
      kRem   -= sel[1];
    }
    Tg = prefix; kRemF = kRem; cntEq = sel[2];
    // band-safety guard: threshold must sit safely above gelu(T0)
    float fTg = __uint_as_float(tg_dec(Tg));
    if (!(fTg > TG_GT0)) slow = true;
  }

  if (slow) {
    // ---- general path: gelu + radix over all 4096 elements (rare) ----
#pragma unroll
    for (int e = 0; e < 16; ++e) gk[e] = tg_key(tg_gelu(xv[e]));
    unsigned prefix = 0, kRem = k;
#pragma unroll
    for (int p = 0; p < 4; ++p) {
      const int shift = 24 - 8 * p;
      __syncthreads();
      hist[0][tid] = 0; hist[1][tid] = 0; hist[2][tid] = 0; hist[3][tid] = 0;
      __syncthreads();
      const unsigned pmask = p ? (0xFFFFFFFFu << (shift + 8)) : 0u;
#pragma unroll
      for (int e = 0; e < 16; ++e)
        if ((gk[e] & pmask) == prefix) atomicAdd(&hist[wv][(gk[e] >> shift) & 255], 1u);
      tg_pick_byte(hist, wtot, sel, kRem, tid, lane, wv);
      prefix |= sel[0] << shift;
      kRem   -= sel[1];
    }
    Tg = prefix; kRemF = kRem; cntEq = sel[2];
  }

  // ---- tie handling: only when #equal != #to-keep (almost never) ----
  const bool needTie = (cntEq != kRemF);
  if (needTie) {
    if (tid < 128) tieMask[tid] = 0;
    __syncthreads();
    if (slow) {
#pragma unroll
      for (int e = 0; e < 16; ++e)
        if (gk[e] == Tg) {
          unsigned s = (unsigned)((tid + (e >> 2) * TG_BLK) * 4 + (e & 3));
          atomicOr(&tieMask[s >> 5], 1u << (s & 31));
        }
    } else {
      unsigned p = base;
#pragma unroll
      for (int e = 0; e < 16; ++e)
        if (candMask & (1u << e)) {
          if (ckey[p] == Tg) {
            unsigned s = (unsigned)((tid + (e >> 2) * TG_BLK) * 4 + (e & 3));
            atomicOr(&tieMask[s >> 5], 1u << (s & 31));
          }
          ++p;
        }
    }
    __syncthreads();
  }

  // ---- per-element verdict + coalesced float4 store ----
  unsigned p = base;
#pragma unroll
  for (int c = 0; c < 4; ++c) {
    float r[4];
#pragma unroll
    for (int j = 0; j < 4; ++j) {
      const int e = 4 * c + j;
      float ov = 0.0f;
      unsigned kk = 0;
      bool have;
      if (slow) { kk = gk[e]; have = true; }
      else { have = (candMask >> e) & 1u; if (have) kk = ckey[p++]; }
      if (have) {
        bool keep = (kk > Tg);
        if (!keep && kk == Tg) {
          if (!needTie) keep = true;
          else {
            unsigned s = (unsigned)((tid + c * TG_BLK) * 4 + j);
            unsigned rank = __popc(tieMask[s >> 5] & ((1u << (s & 31)) - 1u));
            for (unsigned w = 0; w < (s >> 5); ++w) rank += __popc(tieMask[w]);
            keep = rank < kRemF;
          }
        }
        if (keep) ov = __uint_as_float(tg_dec(kk));
      }
      r[j] = ov;
    }
    float4 o4; o4.x = r[0]; o4.y = r[1]; o4.z = r[2]; o4.w = r[3];
    reinterpret_cast<float4*>(outr)[tid + c * TG_BLK] = o4;
  }
}

extern "C" void kernel_launch(void* const* d_in, const int* in_sizes, int n_in,
                              void* d_out, int out_size, void* d_ws, size_t ws_size,
                              hipStream_t stream) {
  const float* x = (const float*)d_in[0];
  const int* kp  = (const int*)d_in[1];
  float* out     = (float*)d_out;
  int rows = in_sizes[0] / TG_D;
  topk_gelu_kernel<<<rows, TG_BLK, 0, stream>>>(x, kp, out);
}

// Round 4
// 101.215 us; speedup vs baseline: 1.5770x; 1.2566x over previous
//
#include <hip/hip_runtime.h>

#define TG_D    4096
#define TG_BLK  256
#define TG_CAP  896
#define TG_T0   0.90f
#define TG_P16G 0xBF40u   // boundary bin floor guard: g >= 0.75 > gelu(0.9)

__device__ __forceinline__ unsigned tg_key(float f) {
  unsigned b = __float_as_uint(f);
  return (b & 0x80000000u) ? ~b : (b | 0x80000000u);
}
__device__ __forceinline__ unsigned tg_dec(unsigned k) {
  return (k & 0x80000000u) ? (k & 0x7FFFFFFFu) : ~k;
}

// Bit-exact replication of jax.nn.gelu(approximate=False) (verified r1-r3:
// absmax == bf16 storage ulp across all rows). Do not touch.
__device__ __forceinline__ float tg_gelu(float x) {
#pragma clang fp contract(off)
  float d  = x / 0x1.6a09e6p+0f;            // IEEE divide by float32(sqrt(2))
  float xc = fmaxf(fminf(d, 4.0f), -4.0f);
  float x2 = xc * xc;
  float p = -2.72614225801306e-10f;
  p = __builtin_fmaf(p, x2,  2.77068142495902e-08f);
  p = __builtin_fmaf(p, x2, -2.10102402082508e-06f);
  p = __builtin_fmaf(p, x2, -5.69250639462346e-05f);
  p = __builtin_fmaf(p, x2, -7.34990630326855e-04f);
  p = __builtin_fmaf(p, x2, -2.95459980854025e-03f);
  p = __builtin_fmaf(p, x2, -1.60960333262415e-02f);
  float q = -1.45660718464996e-05f;
  q = __builtin_fmaf(q, x2, -2.13374055278905e-04f);
  q = __builtin_fmaf(q, x2, -1.68282697438203e-03f);
  q = __builtin_fmaf(q, x2, -7.37332916720468e-03f);
  q = __builtin_fmaf(q, x2, -1.42647390514189e-02f);
  float num = xc * p;
  float e   = num / q;                      // IEEE divide
  float s   = e + 1.0f;
  float m   = x * s;
  return m * 0.5f;
}

// r3's pick (slow path only): sel[0]=byte, sel[1]=strictly-greater, sel[2]=bin count.
__device__ __forceinline__ void tg_pick_byte(unsigned (*h)[256], unsigned* wtot,
                                             unsigned* sel, unsigned kRem,
                                             int tid, int lane, int wv) {
  __syncthreads();
  unsigned cb = h[0][tid] + h[1][tid] + h[2][tid] + h[3][tid];
  unsigned v = cb;
#pragma unroll
  for (int d = 1; d < 64; d <<= 1) {
    unsigned o = __shfl_down(v, d, 64);
    v += (lane + d < 64) ? o : 0u;
  }
  if (lane == 0) wtot[wv] = v;
  __syncthreads();
  unsigned hi = 0;
#pragma unroll
  for (int w = 0; w < 4; ++w)
    if (w > wv) hi += wtot[w];
  unsigned sGE = v + hi, sGT = sGE - cb;
  if (sGE >= kRem && sGT < kRem) { sel[0] = (unsigned)tid; sel[1] = sGT; sel[2] = cb; }
  __syncthreads();
}

__global__ __launch_bounds__(TG_BLK) void topk_gelu_kernel(
    const float* __restrict__ x, const int* __restrict__ kptr,
    float* __restrict__ out) {
  __shared__ unsigned       ckey[TG_CAP];
  __shared__ unsigned short cidx[TG_CAP];
  __shared__ alignas(16) unsigned char uraw[TG_D * 4]; // phase A: cx+hist; phase B: obuf
  __shared__ unsigned       skey[64];
  __shared__ unsigned short scidx[64];
  __shared__ unsigned short scpos[64];
  __shared__ unsigned       tieMask[128];
  __shared__ unsigned       wtot[4];
  __shared__ unsigned       sel[3];
  __shared__ unsigned       cnt2, mCnt;

  float*    cx  = (float*)uraw;                                   // [TG_CAP]
  unsigned (*hist)[256] = (unsigned (*)[256])(uraw + sizeof(float) * TG_CAP);
  float*    obuf = (float*)uraw;                                  // [TG_D] later

  const int tid = threadIdx.x, lane = tid & 63, wv = tid >> 6;
  const unsigned k = (unsigned)(*kptr);
  const float* xr   = x   + (size_t)blockIdx.x * TG_D;
  float*       outr = out + (size_t)blockIdx.x * TG_D;

  // init (covered by B1)
  hist[0][tid] = 0; hist[1][tid] = 0; hist[2][tid] = 0; hist[3][tid] = 0;
  if (tid == 0) { cnt2 = 0; mCnt = 0; sel[0] = 0; sel[1] = 0; sel[2] = 0; }

  // ---- coalesced load, elements stay in VGPRs ----
  float xv[16];
#pragma unroll
  for (int c = 0; c < 4; ++c) {
    float4 v = reinterpret_cast<const float4*>(xr)[tid + c * TG_BLK];
    xv[4*c+0] = v.x; xv[4*c+1] = v.y; xv[4*c+2] = v.z; xv[4*c+3] = v.w;
  }

  // ---- candidate mask + block scan ----
  unsigned candMask = 0;
#pragma unroll
  for (int e = 0; e < 16; ++e)
    if (xv[e] >= TG_T0) candMask |= (1u << e);
  const unsigned cnt = (unsigned)__popc(candMask);
  unsigned inc = cnt;
#pragma unroll
  for (int d = 1; d < 64; d <<= 1) {
    unsigned o = __shfl_up(inc, d, 64);
    if (lane >= d) inc += o;
  }
  if (lane == 63) wtot[wv] = inc;
  __syncthreads();                                   // B1
  unsigned base = inc - cnt;
#pragma unroll
  for (int w = 0; w < 4; ++w) if (w < wv) base += wtot[w];
  const unsigned n0 = wtot[0] + wtot[1] + wtot[2] + wtot[3];
  const unsigned nC = n0 < (unsigned)TG_CAP ? n0 : (unsigned)TG_CAP;

  if (n0 <= (unsigned)TG_CAP) {
    unsigned p = base;
#pragma unroll
    for (int e = 0; e < 16; ++e)
      if (candMask & (1u << e)) {
        cx[p]   = xv[e];
        cidx[p] = (unsigned short)((tid + (e >> 2) * TG_BLK) * 4 + (e & 3));
        ++p;
      }
  }
  __syncthreads();                                   // B2

  // ---- dense gelu + byte1 histogram + c2 (auto-keep) count ----
  unsigned myc2 = 0;
  for (unsigned i = tid; i < nC; i += TG_BLK) {
    unsigned kk = tg_key(tg_gelu(cx[i]));
    ckey[i] = kk;
    if (kk >= 0xC0000000u) ++myc2;
    else atomicAdd(&hist[wv][(kk >> 16) & 255], 1u);
  }
#pragma unroll
  for (int d = 1; d < 64; d <<= 1) {
    unsigned o = __shfl_down(myc2, d, 64);
    myc2 += (lane + d < 64) ? o : 0u;
  }
  if (lane == 0 && myc2) atomicAdd(&cnt2, myc2);
  __syncthreads();                                   // B3

  // ---- single pick over byte1 ----
  const unsigned c2v  = cnt2;
  const unsigned kRem = k - c2v;              // underflow -> no crossing -> slow
  unsigned cb = hist[0][tid] + hist[1][tid] + hist[2][tid] + hist[3][tid];
  unsigned v = cb;
#pragma unroll
  for (int d = 1; d < 64; d <<= 1) {
    unsigned o = __shfl_down(v, d, 64);
    v += (lane + d < 64) ? o : 0u;
  }
  if (lane == 0) wtot[wv] = v;
  __syncthreads();                                   // B4
  unsigned hi = 0;
#pragma unroll
  for (int w = 0; w < 4; ++w) if (w > wv) hi += wtot[w];
  {
    unsigned sGE = v + hi, sGT = sGE - cb;
    if (sGE >= kRem && sGT < kRem) { sel[0] = (unsigned)tid; sel[1] = sGT; sel[2] = cb; }
  }
  __syncthreads();                                   // B5

  const unsigned p16   = 0xBF00u | sel[0];
  const unsigned kRem2 = kRem - sel[1];
  const unsigned m     = sel[2];
  const bool slow = (n0 > (unsigned)TG_CAP) || (c2v >= k) || (p16 < TG_P16G) ||
                    (m > 64u) || (kRem2 == 0u) || (kRem2 > m);

  if (slow) {
    // ---- general path (r3, proven): full-row 4-pass radix + tie bitmap ----
    unsigned gk[16];
#pragma unroll
    for (int e = 0; e < 16; ++e) gk[e] = tg_key(tg_gelu(xv[e]));
    unsigned prefix = 0, kRemS = k;
#pragma unroll
    for (int ps = 0; ps < 4; ++ps) {
      const int shift = 24 - 8 * ps;
      __syncthreads();
      hist[0][tid] = 0; hist[1][tid] = 0; hist[2][tid] = 0; hist[3][tid] = 0;
      __syncthreads();
      const unsigned pmask = ps ? (0xFFFFFFFFu << (shift + 8)) : 0u;
#pragma unroll
      for (int e = 0; e < 16; ++e)
        if ((gk[e] & pmask) == prefix) atomicAdd(&hist[wv][(gk[e] >> shift) & 255], 1u);
      tg_pick_byte(hist, wtot, sel, kRemS, tid, lane, wv);
      prefix |= sel[0] << shift;
      kRemS  -= sel[1];
    }
    const unsigned Tg = prefix, kRemF = kRemS, cntEq = sel[2];
    const bool needTie = (cntEq != kRemF);
    if (needTie) {
      if (tid < 128) tieMask[tid] = 0;
      __syncthreads();
#pragma unroll
      for (int e = 0; e < 16; ++e)
        if (gk[e] == Tg) {
          unsigned s = (unsigned)((tid + (e >> 2) * TG_BLK) * 4 + (e & 3));
          atomicOr(&tieMask[s >> 5], 1u << (s & 31));
        }
      __syncthreads();
    }
#pragma unroll
    for (int c = 0; c < 4; ++c) {
      float r[4];
#pragma unroll
      for (int j = 0; j < 4; ++j) {
        const int e = 4 * c + j;
        unsigned kk = gk[e];
        bool keep = kk > Tg;
        if (!keep && kk == Tg) {
          if (!needTie) keep = true;
          else {
            unsigned s = (unsigned)((tid + c * TG_BLK) * 4 + j);
            unsigned rank = __popc(tieMask[s >> 5] & ((1u << (s & 31)) - 1u));
            for (unsigned w = 0; w < (s >> 5); ++w) rank += __popc(tieMask[w]);
            keep = rank < kRemF;
          }
        }
        r[j] = keep ? __uint_as_float(tg_dec(kk)) : 0.0f;
      }
      float4 o4; o4.x = r[0]; o4.y = r[1]; o4.z = r[2]; o4.w = r[3];
      reinterpret_cast<float4*>(outr)[tid + c * TG_BLK] = o4;
    }
    return;
  }

  // ---- gather boundary-bin survivors (~6 expected, guarded <= 64) ----
  for (unsigned i = tid; i < n0; i += TG_BLK) {
    unsigned kk = ckey[i];
    if ((kk >> 16) == p16) {
      unsigned p = atomicAdd(&mCnt, 1u);
      if (p < 64u) { skey[p] = kk; scidx[p] = cidx[i]; scpos[p] = (unsigned short)i; }
    }
  }
  __syncthreads();                                   // B6

  // ---- wave 0: rank survivors (key desc, index asc), verdict into ckey ----
  if (wv == 0) {
    unsigned myk = (lane < (int)m) ? skey[lane] : 0u;
    unsigned myi = (lane < (int)m) ? (unsigned)scidx[lane] : 0xFFFFu;
    unsigned gt = 0, tr = 0;
    for (unsigned j = 0; j < m; ++j) {
      unsigned kj = __shfl(myk, (int)j, 64);
      unsigned ij = __shfl(myi, (int)j, 64);
      gt += (kj > myk) ? 1u : 0u;
      tr += (kj == myk && ij < myi) ? 1u : 0u;
    }
    if (lane < (int)m) ckey[scpos[lane]] = ((gt + tr) < kRem2) ? myk : 0u;
  }
  // all waves: zero output overlay (cx/hist dead; disjoint from skey/ckey)
  {
    float4 z4; z4.x = 0.f; z4.y = 0.f; z4.z = 0.f; z4.w = 0.f;
#pragma unroll
    for (int w = 0; w < 4; ++w)
      reinterpret_cast<float4*>(obuf)[tid + w * TG_BLK] = z4;
  }
  __syncthreads();                                   // B7

  // ---- dense scatter of kept values: keep <=> (key>>16) >= p16 ----
  for (unsigned i = tid; i < n0; i += TG_BLK) {
    unsigned kk = ckey[i];
    if ((kk >> 16) >= p16) obuf[cidx[i]] = __uint_as_float(tg_dec(kk));
  }
  __syncthreads();                                   // B8

  // ---- coalesced float4 store ----
#pragma unroll
  for (int c = 0; c < 4; ++c) {
    float4 o4 = reinterpret_cast<const float4*>(obuf)[tid + c * TG_BLK];
    reinterpret_cast<float4*>(outr)[tid + c * TG_BLK] = o4;
  }
}

extern "C" void kernel_launch(void* const* d_in, const int* in_sizes, int n_in,
                              void* d_out, int out_size, void* d_ws, size_t ws_size,
                              hipStream_t stream) {
  const float* x = (const float*)d_in[0];
  const int* kp  = (const int*)d_in[1];
  float* out     = (float*)d_out;
  int rows = in_sizes[0] / TG_D;
  topk_gelu_kernel<<<rows, TG_BLK, 0, stream>>>(x, kp, out);
}

// Round 5
// 85.414 us; speedup vs baseline: 1.8687x; 1.1850x over previous
//
#include <hip/hip_runtime.h>

#define TG_D    4096
#define TG_BLK  256
#define TG_CAP  832
#define TG_T0   1.00f
// bin-floor guard (float-bits domain): threshold bin must be >= 0x3F58,
// i.e. g* >= 0.84375 > gelu(1.0) = 0.841345 -> no non-candidate can qualify.
#define TG_BING 0x3F58u

typedef float v4f __attribute__((ext_vector_type(4)));

__device__ __forceinline__ unsigned tg_key(float f) {   // slow path only
  unsigned b = __float_as_uint(f);
  return (b & 0x80000000u) ? ~b : (b | 0x80000000u);
}
__device__ __forceinline__ unsigned tg_dec(unsigned k) {
  return (k & 0x80000000u) ? (k & 0x7FFFFFFFu) : ~k;
}

// Bit-exact replication of jax.nn.gelu(approximate=False) (verified r1-r4:
// absmax == bf16 storage ulp across all rows). Do not touch.
__device__ __forceinline__ float tg_gelu(float x) {
#pragma clang fp contract(off)
  float d  = x / 0x1.6a09e6p+0f;            // IEEE divide by float32(sqrt(2))
  float xc = fmaxf(fminf(d, 4.0f), -4.0f);
  float x2 = xc * xc;
  float p = -2.72614225801306e-10f;
  p = __builtin_fmaf(p, x2,  2.77068142495902e-08f);
  p = __builtin_fmaf(p, x2, -2.10102402082508e-06f);
  p = __builtin_fmaf(p, x2, -5.69250639462346e-05f);
  p = __builtin_fmaf(p, x2, -7.34990630326855e-04f);
  p = __builtin_fmaf(p, x2, -2.95459980854025e-03f);
  p = __builtin_fmaf(p, x2, -1.60960333262415e-02f);
  float q = -1.45660718464996e-05f;
  q = __builtin_fmaf(q, x2, -2.13374055278905e-04f);
  q = __builtin_fmaf(q, x2, -1.68282697438203e-03f);
  q = __builtin_fmaf(q, x2, -7.37332916720468e-03f);
  q = __builtin_fmaf(q, x2, -1.42647390514189e-02f);
  float num = xc * p;
  float e   = num / q;                      // IEEE divide
  float s   = e + 1.0f;
  float m   = x * s;
  return m * 0.5f;
}

// slow-path pick: sel[0]=byte, sel[1]=strictly-greater, sel[2]=bin count.
__device__ __forceinline__ void tg_pick_byte(unsigned (*h)[256], unsigned* wtot,
                                             unsigned* sel, unsigned kRem,
                                             int tid, int lane, int wv) {
  __syncthreads();
  unsigned cb = h[0][tid] + h[1][tid] + h[2][tid] + h[3][tid];
  unsigned v = cb;
#pragma unroll
  for (int d = 1; d < 64; d <<= 1) {
    unsigned o = __shfl_down(v, d, 64);
    v += (lane + d < 64) ? o : 0u;
  }
  if (lane == 0) wtot[wv] = v;
  __syncthreads();
  unsigned hi = 0;
#pragma unroll
  for (int w = 0; w < 4; ++w)
    if (w > wv) hi += wtot[w];
  unsigned sGE = v + hi, sGT = sGE - cb;
  if (sGE >= kRem && sGT < kRem) { sel[0] = (unsigned)tid; sel[1] = sGT; sel[2] = cb; }
  __syncthreads();
}

__global__ __launch_bounds__(TG_BLK) void topk_gelu_kernel(
    const float* __restrict__ x, const int* __restrict__ kptr,
    float* __restrict__ out) {
  __shared__ float          cx[TG_CAP];      // candidate x (thread-major)
  __shared__ unsigned       ckey[TG_CAP];    // candidate gelu float-bits
  __shared__ unsigned short cidx[TG_CAP];    // candidate row position
  __shared__ unsigned       hist[4][256];
  __shared__ unsigned       skey[64];
  __shared__ unsigned short scidx[64];
  __shared__ unsigned short scpos[64];
  __shared__ unsigned       tieMask[128];
  __shared__ unsigned       wtot[4];
  __shared__ unsigned       sel[3];
  __shared__ unsigned       cnt2, mCnt;

  const int tid = threadIdx.x, lane = tid & 63, wv = tid >> 6;
  const unsigned k = (unsigned)(*kptr);
  const float* xr   = x   + (size_t)blockIdx.x * TG_D;
  float*       outr = out + (size_t)blockIdx.x * TG_D;

  hist[0][tid] = 0; hist[1][tid] = 0; hist[2][tid] = 0; hist[3][tid] = 0;
  if (tid == 0) { cnt2 = 0; mCnt = 0; sel[0] = 0; sel[1] = 0; sel[2] = 0; }

  // ---- coalesced load, elements stay in VGPRs ----
  float xv[16];
#pragma unroll
  for (int c = 0; c < 4; ++c) {
    float4 v = reinterpret_cast<const float4*>(xr)[tid + c * TG_BLK];
    xv[4*c+0] = v.x; xv[4*c+1] = v.y; xv[4*c+2] = v.z; xv[4*c+3] = v.w;
  }

  // ---- candidate mask + block scan ----
  unsigned candMask = 0;
#pragma unroll
  for (int e = 0; e < 16; ++e)
    if (xv[e] >= TG_T0) candMask |= (1u << e);
  const unsigned cnt = (unsigned)__popc(candMask);
  unsigned inc = cnt;
#pragma unroll
  for (int d = 1; d < 64; d <<= 1) {
    unsigned o = __shfl_up(inc, d, 64);
    if (lane >= d) inc += o;
  }
  if (lane == 63) wtot[wv] = inc;
  __syncthreads();                                   // B1
  unsigned base = inc - cnt;
#pragma unroll
  for (int w = 0; w < 4; ++w) if (w < wv) base += wtot[w];
  const unsigned n0 = wtot[0] + wtot[1] + wtot[2] + wtot[3];
  const unsigned nC = n0 < (unsigned)TG_CAP ? n0 : (unsigned)TG_CAP;

  if (n0 <= (unsigned)TG_CAP) {
    unsigned p = base;
#pragma unroll
    for (int e = 0; e < 16; ++e)
      if (candMask & (1u << e)) {
        cx[p]   = xv[e];
        cidx[p] = (unsigned short)((tid + (e >> 2) * TG_BLK) * 4 + (e & 3));
        ++p;
      }
  }
  __syncthreads();                                   // B2

  // ---- dense gelu (float-bits domain) + byte1 hist + auto-keep count ----
  unsigned myc2 = 0;
  for (unsigned i = tid; i < nC; i += TG_BLK) {
    unsigned gb = __float_as_uint(tg_gelu(cx[i]));   // all positive here
    ckey[i] = gb;
    if (gb >= 0x40000000u) ++myc2;                   // g >= 2.0: auto-keep
    else atomicAdd(&hist[wv][(gb >> 16) & 255], 1u);
  }
#pragma unroll
  for (int d = 1; d < 64; d <<= 1) {
    unsigned o = __shfl_down(myc2, d, 64);
    myc2 += (lane + d < 64) ? o : 0u;
  }
  if (lane == 0 && myc2) atomicAdd(&cnt2, myc2);
  __syncthreads();                                   // B3

  // ---- single pick over bits[23:16] ----
  const unsigned c2v  = cnt2;
  const unsigned kRem = k - c2v;                     // underflow -> no crossing
  unsigned cb = hist[0][tid] + hist[1][tid] + hist[2][tid] + hist[3][tid];
  unsigned v = cb;
#pragma unroll
  for (int d = 1; d < 64; d <<= 1) {
    unsigned o = __shfl_down(v, d, 64);
    v += (lane + d < 64) ? o : 0u;
  }
  if (lane == 0) wtot[wv] = v;
  __syncthreads();                                   // B4
  unsigned hi = 0;
#pragma unroll
  for (int w = 0; w < 4; ++w) if (w > wv) hi += wtot[w];
  {
    unsigned sGE = v + hi, sGT = sGE - cb;
    if (sGE >= kRem && sGT < kRem) { sel[0] = (unsigned)tid; sel[1] = sGT; sel[2] = cb; }
  }
  __syncthreads();                                   // B5

  const unsigned bin   = 0x3F00u | sel[0];           // full bits[31:16] of bin
  const unsigned kRem2 = kRem - sel[1];
  const unsigned m     = sel[2];
  const bool slow = (n0 > (unsigned)TG_CAP) || (n0 < k + 32u) || (c2v >= k) ||
                    (bin < TG_BING) || (m > 64u) || (kRem2 == 0u) || (kRem2 > m);

  if (slow) {
    // ---- general path (r3/r4, proven): full-row keyed radix + tie bitmap ----
    unsigned gk[16];
#pragma unroll
    for (int e = 0; e < 16; ++e) gk[e] = tg_key(tg_gelu(xv[e]));
    unsigned prefix = 0, kRemS = k;
#pragma unroll
    for (int ps = 0; ps < 4; ++ps) {
      const int shift = 24 - 8 * ps;
      __syncthreads();
      hist[0][tid] = 0; hist[1][tid] = 0; hist[2][tid] = 0; hist[3][tid] = 0;
      __syncthreads();
      const unsigned pmask = ps ? (0xFFFFFFFFu << (shift + 8)) : 0u;
#pragma unroll
      for (int e = 0; e < 16; ++e)
        if ((gk[e] & pmask) == prefix) atomicAdd(&hist[wv][(gk[e] >> shift) & 255], 1u);
      tg_pick_byte(hist, wtot, sel, kRemS, tid, lane, wv);
      prefix |= sel[0] << shift;
      kRemS  -= sel[1];
    }
    const unsigned Tg = prefix, kRemF = kRemS, cntEq = sel[2];
    const bool needTie = (cntEq != kRemF);
    if (needTie) {
      if (tid < 128) tieMask[tid] = 0;
      __syncthreads();
#pragma unroll
      for (int e = 0; e < 16; ++e)
        if (gk[e] == Tg) {
          unsigned s = (unsigned)((tid + (e >> 2) * TG_BLK) * 4 + (e & 3));
          atomicOr(&tieMask[s >> 5], 1u << (s & 31));
        }
      __syncthreads();
    }
#pragma unroll
    for (int c = 0; c < 4; ++c) {
      float r[4];
#pragma unroll
      for (int j = 0; j < 4; ++j) {
        const int e = 4 * c + j;
        unsigned kk = gk[e];
        bool keep = kk > Tg;
        if (!keep && kk == Tg) {
          if (!needTie) keep = true;
          else {
            unsigned s = (unsigned)((tid + c * TG_BLK) * 4 + j);
            unsigned rank = __popc(tieMask[s >> 5] & ((1u << (s & 31)) - 1u));
            for (unsigned w = 0; w < (s >> 5); ++w) rank += __popc(tieMask[w]);
            keep = rank < kRemF;
          }
        }
        r[j] = keep ? __uint_as_float(tg_dec(kk)) : 0.0f;
      }
      v4f o4 = { r[0], r[1], r[2], r[3] };
      __builtin_nontemporal_store(o4, reinterpret_cast<v4f*>(outr) + tid + c * TG_BLK);
    }
    return;
  }

  // ---- gather boundary-bin survivors (~6 expected, guarded <= 64) ----
  for (unsigned i = tid; i < n0; i += TG_BLK) {
    unsigned gb = ckey[i];
    if ((gb >> 16) == bin) {
      unsigned p = atomicAdd(&mCnt, 1u);
      if (p < 64u) { skey[p] = gb; scidx[p] = cidx[i]; scpos[p] = (unsigned short)i; }
    }
  }
  __syncthreads();                                   // B6

  // ---- wave 0: rank survivors (g desc, index asc), verdict into ckey ----
  if (wv == 0) {
    unsigned myk = (lane < (int)m) ? skey[lane] : 0u;
    unsigned myi = (lane < (int)m) ? (unsigned)scidx[lane] : 0xFFFFu;
    unsigned gt = 0, tr = 0;
    for (unsigned j = 0; j < m; ++j) {
      unsigned kj = __shfl(myk, (int)j, 64);
      unsigned ij = __shfl(myi, (int)j, 64);
      gt += (kj > myk) ? 1u : 0u;
      tr += (kj == myk && ij < myi) ? 1u : 0u;
    }
    if (lane < (int)m) ckey[scpos[lane]] = ((gt + tr) < kRem2) ? myk : 0u;
  }
  __syncthreads();                                   // B7

  // ---- per-thread verdict (sequential ckey reads) + nontemporal store ----
  const unsigned thr = bin << 16;
  unsigned p = base;
#pragma unroll
  for (int c = 0; c < 4; ++c) {
    float r[4];
#pragma unroll
    for (int j = 0; j < 4; ++j) {
      const int e = 4 * c + j;
      float ov = 0.0f;
      if (candMask & (1u << e)) {
        unsigned gb = ckey[p++];
        if (gb >= thr) ov = __uint_as_float(gb);
      }
      r[j] = ov;
    }
    v4f o4 = { r[0], r[1], r[2], r[3] };
    __builtin_nontemporal_store(o4, reinterpret_cast<v4f*>(outr) + tid + c * TG_BLK);
  }
}

extern "C" void kernel_launch(void* const* d_in, const int* in_sizes, int n_in,
                              void* d_out, int out_size, void* d_ws, size_t ws_size,
                              hipStream_t stream) {
  const float* x = (const float*)d_in[0];
  const int* kp  = (const int*)d_in[1];
  float* out     = (float*)d_out;
  int rows = in_sizes[0] / TG_D;
  topk_gelu_kernel<<<rows, TG_BLK, 0, stream>>>(x, kp, out);
}